// Round 1
// baseline (181.601 us; speedup 1.0000x reference)
//
#include <hip/hip_runtime.h>

#define B_   16
#define C_   64
#define N_   2048
#define M_   (B_ * N_)     // 32768 points
#define K_   20
#define KS_  20
#define OC_  64
#define NWAVE2 8192        // waves in k_points (2048 blocks x 4 waves)
#define NBLK2  2048        // blocks in k_points

// ---------------------------------------------------------------------------
// K1: P[m][o] = sum_c W2[o][c]*flat[m][c];  Q[m][o] = sum_c (W1-W2)[o][c]*flat[m][c]
// wave = 64 lanes, lane = o. Weights in 128 VGPRs, feature broadcast via
// readlane. 4 accumulator chains to cover FMA latency.
// ---------------------------------------------------------------------------
__global__ __launch_bounds__(256) void k_project(
    const float* __restrict__ feat,     // [B][C][N]
    const float* __restrict__ conv_w,   // [OC][2C]
    float* __restrict__ pq)             // [M][128]
{
    const int lane = threadIdx.x & 63;
    const int wg   = blockIdx.x * 4 + (threadIdx.x >> 6);   // 0..2047
    float w2[64], wd[64];
    const float4* cw4 = (const float4*)conv_w;
    #pragma unroll
    for (int j = 0; j < 16; ++j) {
        float4 a = cw4[lane * 32 + j];        // W1 chunk
        float4 b = cw4[lane * 32 + 16 + j];   // W2 chunk
        w2[4*j+0] = b.x; w2[4*j+1] = b.y; w2[4*j+2] = b.z; w2[4*j+3] = b.w;
        wd[4*j+0] = a.x - b.x; wd[4*j+1] = a.y - b.y;
        wd[4*j+2] = a.z - b.z; wd[4*j+3] = a.w - b.w;
    }
    const int m0 = wg * 16;
    int b0 = m0 >> 11, p0 = m0 & 2047;
    float fv = feat[((size_t)(b0 * 64 + lane)) * 2048 + p0];
    for (int mi = 0; mi < 16; ++mi) {
        const int m = m0 + mi;
        float fnext = 0.f;
        if (mi < 15) {
            const int mn = m + 1;
            fnext = feat[((size_t)((mn >> 11) * 64 + lane)) * 2048 + (mn & 2047)];
        }
        float p0a = 0.f, p1a = 0.f, q0a = 0.f, q1a = 0.f;
        #pragma unroll
        for (int c = 0; c < 32; ++c) {
            float f0 = __int_as_float(
                __builtin_amdgcn_readlane(__float_as_int(fv), c));
            float f1 = __int_as_float(
                __builtin_amdgcn_readlane(__float_as_int(fv), c + 32));
            p0a = fmaf(w2[c], f0, p0a);
            p1a = fmaf(w2[c + 32], f1, p1a);
            q0a = fmaf(wd[c], f0, q0a);
            q1a = fmaf(wd[c + 32], f1, q1a);
        }
        pq[(size_t)m * 128 + lane]      = p0a + p1a;
        pq[(size_t)m * 128 + 64 + lane] = q0a + q1a;
        fv = fnext;
    }
}

// ---------------------------------------------------------------------------
// broadcast element E (0..399) of the wave-distributed perm row.
// pa: elems 0..255 (lane e>>2, comp e&3 across all 64 lanes)
// pb: elems 256..399 (lanes 0..35)
// E is a compile-time constant -> v_readlane_b32 with immediate lane index.
// ---------------------------------------------------------------------------
template<int E>
__device__ __forceinline__ float bro(const float4& pa, const float4& pb) {
    constexpr int c = E & 3;
    float v;
    if constexpr (E < 256) {
        if constexpr (c == 0) v = pa.x; else if constexpr (c == 1) v = pa.y;
        else if constexpr (c == 2) v = pa.z; else v = pa.w;
    } else {
        if constexpr (c == 0) v = pb.x; else if constexpr (c == 1) v = pb.y;
        else if constexpr (c == 2) v = pb.z; else v = pb.w;
    }
    constexpr int l = (E < 256) ? (E >> 2) : ((E >> 2) - 64);
    return __int_as_float(__builtin_amdgcn_readlane(__float_as_int(v), l));
}

#define KS1(K,S) acc[S] = fmaf(t, bro<(K)*20+(S)>(pa, pb), acc[S]);
#define KSTEP(K) { const float t = pk[K] + q; \
    KS1(K,0)  KS1(K,1)  KS1(K,2)  KS1(K,3)  KS1(K,4)  \
    KS1(K,5)  KS1(K,6)  KS1(K,7)  KS1(K,8)  KS1(K,9)  \
    KS1(K,10) KS1(K,11) KS1(K,12) KS1(K,13) KS1(K,14) \
    KS1(K,15) KS1(K,16) KS1(K,17) KS1(K,18) KS1(K,19) }

// ---------------------------------------------------------------------------
// one point of K2: gathers + 20x20 FMA block + max + BN partial accumulation.
// perm row for THIS point already resident in (pa,pb); next point's row is
// prefetched into (npa,npb) before the FMA block so its latency hides there.
// All waits are compiler-inserted per-register vmcnt (no LDS, no manual cnt).
// ---------------------------------------------------------------------------
template<bool PREF>
__device__ __forceinline__ void point_step(
    int n, int lane, float bias, int& iv,
    float4& pa, float4& pb, float4& npa, float4& npb,
    const float* __restrict__ pq, const int* __restrict__ nidx,
    const float* __restrict__ perm,
    float* __restrict__ pre, float& sum, float& sumsq)
{
    // broadcast idx values to SGPRs (forces wait on the idx vector load)
    int ik[20];
    #pragma unroll
    for (int k = 0; k < 20; ++k) ik[k] = __builtin_amdgcn_readlane(iv, k);
    // gathers: q first, then pk[k] (oldest-first consumption in FMA block)
    float q = pq[(size_t)ik[0] * 128 + 64 + lane];
    float pk[20];
    #pragma unroll
    for (int k = 0; k < 20; ++k) pk[k] = pq[(size_t)ik[k] * 128 + lane];
    // prefetch next point's idx row + perm row into registers; these stay
    // in flight across the FMA block below.
    if (PREF) {
        const int nn = n + NWAVE2;
        if (lane < 20) iv = nidx[(size_t)nn * K_ + lane];
        const float* src = perm + (size_t)nn * 400;
        npa = *(const float4*)(src + lane * 4);
        if (lane < 36) npb = *(const float4*)(src + 256 + lane * 4);
    }

    float acc[20];
    #pragma unroll
    for (int s = 0; s < 20; ++s) acc[s] = bias;
    KSTEP(0)  KSTEP(1)  KSTEP(2)  KSTEP(3)  KSTEP(4)
    KSTEP(5)  KSTEP(6)  KSTEP(7)  KSTEP(8)  KSTEP(9)
    KSTEP(10) KSTEP(11) KSTEP(12) KSTEP(13) KSTEP(14)
    KSTEP(15) KSTEP(16) KSTEP(17) KSTEP(18) KSTEP(19)

    float mv = acc[0];
    #pragma unroll
    for (int s = 1; s < 20; ++s) mv = fmaxf(mv, acc[s]);
    pre[(size_t)n * 64 + lane] = mv;
    sum += mv;
    sumsq = fmaf(mv, mv, sumsq);
}

// ---------------------------------------------------------------------------
// K2: per point n (wave = point, lane = o):
//   pk[k] = P[idx[n,k]][o] + Q[idx[n,0]][o]
//   acc[s] = b[o] + sum_k pk[k]*perm[n][k][s];  pre[n][o] = max_s acc[s]
// perm rows live in wave VGPRs (2 coalesced dwordx4 loads / point, register
// double-buffered); broadcast to the FMA operand via v_readlane (VALU) instead
// of uniform ds_read_b128 broadcasts (LDS pipe was the 63us bottleneck:
// 100 b128 x ~12cyc x 128 points per CU ~= 64us on the single LDS pipe).
// ---------------------------------------------------------------------------
__global__ __launch_bounds__(256) void k_points(
    const float* __restrict__ pq,        // [M][128]
    const int*   __restrict__ nidx,      // [M][K]
    const float* __restrict__ perm,      // [M][K][KS]
    const float* __restrict__ conv_b,    // [OC]
    float* __restrict__ pre,             // [M][OC]
    float* __restrict__ partials)        // [NBLK2][128]
{
    const int tid  = threadIdx.x;
    const int lane = tid & 63;
    const int w    = tid >> 6;
    const int wg   = (int)blockIdx.x * 4 + w;   // wave id 0..8191

    const float bias = conv_b[lane];
    float sum = 0.f, sumsq = 0.f;

    float4 pa, pb, npa, npb;
    int iv = 0;
    {   // prologue: point wg's perm row + idx row
        const float* src = perm + (size_t)wg * 400;
        pa = *(const float4*)(src + lane * 4);
        if (lane < 36) pb = *(const float4*)(src + 256 + lane * 4);
        if (lane < 20) iv = nidx[(size_t)wg * K_ + lane];
    }

    point_step<true >(wg,              lane, bias, iv, pa,  pb,  npa, npb,
                      pq, nidx, perm, pre, sum, sumsq);
    point_step<true >(wg + NWAVE2,     lane, bias, iv, npa, npb, pa,  pb,
                      pq, nidx, perm, pre, sum, sumsq);
    point_step<true >(wg + 2 * NWAVE2, lane, bias, iv, pa,  pb,  npa, npb,
                      pq, nidx, perm, pre, sum, sumsq);
    point_step<false>(wg + 3 * NWAVE2, lane, bias, iv, npa, npb, pa,  pb,
                      pq, nidx, perm, pre, sum, sumsq);

    // block-level BN partial reduction (LDS is free now): 4MB -> 1MB partials
    __shared__ float red[512];
    red[w * 128 + lane]      = sum;
    red[w * 128 + 64 + lane] = sumsq;
    __syncthreads();
    if (tid < 128) {
        float s = red[tid] + red[128 + tid] + red[256 + tid] + red[384 + tid];
        partials[(size_t)blockIdx.x * 128 + tid] = s;
    }
}

#undef KSTEP
#undef KS1

// ---------------------------------------------------------------------------
// K2b: reduce partials per channel, fold BN+gamma/beta into scale/shift.
// ---------------------------------------------------------------------------
__global__ __launch_bounds__(256) void k_stats(
    const float* __restrict__ partials,  // [NBLK2][128]
    const float* __restrict__ gamma,
    const float* __restrict__ beta,
    float* __restrict__ stats)           // [128]
{
    const int ch  = blockIdx.x;          // 0..63
    const int tid = threadIdx.x;
    double s = 0.0, s2 = 0.0;
    for (int w = tid; w < NBLK2; w += 256) {
        s  += (double)partials[(size_t)w * 128 + ch];
        s2 += (double)partials[(size_t)w * 128 + 64 + ch];
    }
    __shared__ double sh_s[256];
    __shared__ double sh_q[256];
    sh_s[tid] = s; sh_q[tid] = s2;
    __syncthreads();
    for (int off = 128; off > 0; off >>= 1) {
        if (tid < off) { sh_s[tid] += sh_s[tid + off]; sh_q[tid] += sh_q[tid + off]; }
        __syncthreads();
    }
    if (tid == 0) {
        const double inv_n = 1.0 / (double)M_;
        double mean = sh_s[0] * inv_n;
        double var  = sh_q[0] * inv_n - mean * mean;
        double inv  = 1.0 / sqrt(var + 1e-5);
        double sc   = (double)gamma[ch] * inv;
        stats[ch]      = (float)sc;
        stats[64 + ch] = (float)((double)beta[ch] - mean * sc);
    }
}

// ---------------------------------------------------------------------------
// K3: y = pre*scale + shift, transposed [M][OC] -> [B][OC][N] via LDS 64x65.
// ---------------------------------------------------------------------------
__global__ __launch_bounds__(256) void k_apply(
    const float* __restrict__ pre,     // [M][OC]
    const float* __restrict__ stats,   // [128]
    float* __restrict__ out)           // [B][OC][N]
{
    __shared__ float tile[64 * 65];
    __shared__ float scl[64];
    __shared__ float shf[64];
    const int tid = threadIdx.x;
    if (tid < 64)       scl[tid]      = stats[tid];
    else if (tid < 128) shf[tid - 64] = stats[tid];
    __syncthreads();
    const int b  = blockIdx.x >> 5;
    const int pt = (blockIdx.x & 31) * 64;
    const int c  = tid & 63;
    const int r0 = tid >> 6;
    #pragma unroll
    for (int i = 0; i < 16; ++i) {
        const int r = i * 4 + r0;
        float v = pre[((size_t)(b * 2048 + pt + r)) * 64 + c];
        tile[c * 65 + r] = fmaf(v, scl[c], shf[c]);
    }
    __syncthreads();
    #pragma unroll
    for (int i = 0; i < 16; ++i) {
        const int o = i * 4 + r0;
        out[((size_t)(b * 64 + o)) * 2048 + pt + c] = tile[o * 65 + c];
    }
}

extern "C" void kernel_launch(void* const* d_in, const int* in_sizes, int n_in,
                              void* d_out, int out_size, void* d_ws, size_t ws_size,
                              hipStream_t stream) {
    const float* feat   = (const float*)d_in[0];
    const int*   nidx   = (const int*)  d_in[1];
    const float* perm   = (const float*)d_in[2];
    const float* conv_w = (const float*)d_in[3];
    const float* conv_b = (const float*)d_in[4];
    const float* gamma  = (const float*)d_in[5];
    const float* beta   = (const float*)d_in[6];
    float* out = (float*)d_out;

    char* ws = (char*)d_ws;
    float* pq       = (float*)ws;                                    // 16 MiB
    float* pre      = (float*)(ws + (size_t)M_ * 128 * 4);           //  8 MiB
    float* partials = (float*)(ws + (size_t)M_ * 128 * 4
                                  + (size_t)M_ * 64 * 4);            //  1 MiB
    float* stats    = (float*)(ws + (size_t)M_ * 128 * 4
                                  + (size_t)M_ * 64 * 4
                                  + (size_t)NBLK2 * 128 * 4);        // 512 B

    hipLaunchKernelGGL(k_project, dim3(512),  dim3(256), 0, stream, feat, conv_w, pq);
    hipLaunchKernelGGL(k_points,  dim3(2048), dim3(256), 0, stream, pq, nidx, perm,
                       conv_b, pre, partials);
    hipLaunchKernelGGL(k_stats,   dim3(64),   dim3(256), 0, stream, partials, gamma,
                       beta, stats);
    hipLaunchKernelGGL(k_apply,   dim3(512),  dim3(256), 0, stream, pre, stats, out);
}

// Round 2
// 181.559 us; speedup vs baseline: 1.0002x; 1.0002x over previous
//
#include <hip/hip_runtime.h>

#define B_   16
#define C_   64
#define N_   2048
#define M_   (B_ * N_)     // 32768 points
#define K_   20
#define KS_  20
#define OC_  64
#define NWAVE2 8192        // waves in k_points (2048 blocks x 4 waves)
#define NBLK2  2048        // blocks in k_points

// ---------------------------------------------------------------------------
// K1: P[m][o] = sum_c W2[o][c]*flat[m][c];  Q[m][o] = sum_c (W1-W2)[o][c]*flat[m][c]
// wave = 64 lanes, lane = o. Weights in 128 VGPRs, feature broadcast via
// readlane. 4 accumulator chains to cover FMA latency.
// ---------------------------------------------------------------------------
__global__ __launch_bounds__(256) void k_project(
    const float* __restrict__ feat,     // [B][C][N]
    const float* __restrict__ conv_w,   // [OC][2C]
    float* __restrict__ pq)             // [M][128]
{
    const int lane = threadIdx.x & 63;
    const int wg   = blockIdx.x * 4 + (threadIdx.x >> 6);   // 0..2047
    float w2[64], wd[64];
    const float4* cw4 = (const float4*)conv_w;
    #pragma unroll
    for (int j = 0; j < 16; ++j) {
        float4 a = cw4[lane * 32 + j];        // W1 chunk
        float4 b = cw4[lane * 32 + 16 + j];   // W2 chunk
        w2[4*j+0] = b.x; w2[4*j+1] = b.y; w2[4*j+2] = b.z; w2[4*j+3] = b.w;
        wd[4*j+0] = a.x - b.x; wd[4*j+1] = a.y - b.y;
        wd[4*j+2] = a.z - b.z; wd[4*j+3] = a.w - b.w;
    }
    const int m0 = wg * 16;
    int b0 = m0 >> 11, p0 = m0 & 2047;
    float fv = feat[((size_t)(b0 * 64 + lane)) * 2048 + p0];
    for (int mi = 0; mi < 16; ++mi) {
        const int m = m0 + mi;
        float fnext = 0.f;
        if (mi < 15) {
            const int mn = m + 1;
            fnext = feat[((size_t)((mn >> 11) * 64 + lane)) * 2048 + (mn & 2047)];
        }
        float p0a = 0.f, p1a = 0.f, q0a = 0.f, q1a = 0.f;
        #pragma unroll
        for (int c = 0; c < 32; ++c) {
            float f0 = __int_as_float(
                __builtin_amdgcn_readlane(__float_as_int(fv), c));
            float f1 = __int_as_float(
                __builtin_amdgcn_readlane(__float_as_int(fv), c + 32));
            p0a = fmaf(w2[c], f0, p0a);
            p1a = fmaf(w2[c + 32], f1, p1a);
            q0a = fmaf(wd[c], f0, q0a);
            q1a = fmaf(wd[c + 32], f1, q1a);
        }
        pq[(size_t)m * 128 + lane]      = p0a + p1a;
        pq[(size_t)m * 128 + 64 + lane] = q0a + q1a;
        fv = fnext;
    }
}

// ---------------------------------------------------------------------------
// broadcast element E (0..399) of the wave-distributed perm row.
// pa: elems 0..255 (lane e>>2, comp e&3); pb: elems 256..399 (lanes 0..35).
// E compile-time -> v_readlane_b32 with immediate lane index.
// ---------------------------------------------------------------------------
template<int E>
__device__ __forceinline__ float bro(const float4& pa, const float4& pb) {
    constexpr int c = E & 3;
    float v;
    if constexpr (E < 256) {
        if constexpr (c == 0) v = pa.x; else if constexpr (c == 1) v = pa.y;
        else if constexpr (c == 2) v = pa.z; else v = pa.w;
    } else {
        if constexpr (c == 0) v = pb.x; else if constexpr (c == 1) v = pb.y;
        else if constexpr (c == 2) v = pb.z; else v = pb.w;
    }
    constexpr int l = (E < 256) ? (E >> 2) : ((E >> 2) - 64);
    return __int_as_float(__builtin_amdgcn_readlane(__float_as_int(v), l));
}

// per-point in-flight state: perm row (8 VGPRs) + 21 gathered floats.
struct Pt { float4 pa, pb; float q; float pk[20]; };

// ---------------------------------------------------------------------------
// issue_point: start ALL memory for point n — 21 pq gathers + perm row.
// Called one full compute-block (~2000 cyc) before consumption, so the
// random-gather L2/L3 latency (~600-900 cyc) is fully covered by the FMA
// block of the previous point (ILP pipelining; TLP alone was insufficient:
// both the LDS and readlane variants measured the same 63us with ~20us of
// exposed gather latency).
// ---------------------------------------------------------------------------
__device__ __forceinline__ void issue_point(
    int n, int lane, int iv,
    const float* __restrict__ pq, const float* __restrict__ perm, Pt& P)
{
    int ik[20];
    #pragma unroll
    for (int k = 0; k < 20; ++k) ik[k] = __builtin_amdgcn_readlane(iv, k);
    P.q = pq[(size_t)ik[0] * 128 + 64 + lane];
    #pragma unroll
    for (int k = 0; k < 20; ++k) P.pk[k] = pq[(size_t)ik[k] * 128 + lane];
    const float* src = perm + (size_t)n * 400;
    P.pa = *(const float4*)(src + lane * 4);
    if (lane < 36) P.pb = *(const float4*)(src + 256 + lane * 4);
}

#define KS1(K,S) acc[S] = fmaf(t, bro<(K)*20+(S)>(pa, pb), acc[S]);
#define KSI(S)   acc[S] = fmaf(t, bro<S>(pa, pb), bias);
#define KSTEP(K) { const float t = P.pk[K] + P.q; \
    KS1(K,0)  KS1(K,1)  KS1(K,2)  KS1(K,3)  KS1(K,4)  \
    KS1(K,5)  KS1(K,6)  KS1(K,7)  KS1(K,8)  KS1(K,9)  \
    KS1(K,10) KS1(K,11) KS1(K,12) KS1(K,13) KS1(K,14) \
    KS1(K,15) KS1(K,16) KS1(K,17) KS1(K,18) KS1(K,19) }
#define KSTEP0 { const float t = P.pk[0] + P.q; \
    KSI(0)  KSI(1)  KSI(2)  KSI(3)  KSI(4)  \
    KSI(5)  KSI(6)  KSI(7)  KSI(8)  KSI(9)  \
    KSI(10) KSI(11) KSI(12) KSI(13) KSI(14) \
    KSI(15) KSI(16) KSI(17) KSI(18) KSI(19) }

// ---------------------------------------------------------------------------
// compute_point: 20x20 FMA block (acc chains identical order to the
// reference-matched original -> bit-identical numerics), max, store,
// BN partial accumulation. Waits are compiler-inserted per-register vmcnt.
// ---------------------------------------------------------------------------
__device__ __forceinline__ void compute_point(
    int n, int lane, float bias, const Pt& P,
    float* __restrict__ pre, float& sum, float& sumsq)
{
    const float4 pa = P.pa, pb = P.pb;
    float acc[20];
    KSTEP0
    KSTEP(1)  KSTEP(2)  KSTEP(3)  KSTEP(4)
    KSTEP(5)  KSTEP(6)  KSTEP(7)  KSTEP(8)  KSTEP(9)
    KSTEP(10) KSTEP(11) KSTEP(12) KSTEP(13) KSTEP(14)
    KSTEP(15) KSTEP(16) KSTEP(17) KSTEP(18) KSTEP(19)

    float mv = acc[0];
    #pragma unroll
    for (int s = 1; s < 20; ++s) mv = fmaxf(mv, acc[s]);
    pre[(size_t)n * 64 + lane] = mv;
    sum += mv;
    sumsq = fmaf(mv, mv, sumsq);
}

// ---------------------------------------------------------------------------
// K2: per point n (wave = point, lane = o):
//   pk[k] = P[idx[n,k]][o] + Q[idx[n,0]][o]
//   acc[s] = b[o] + sum_k pk[k]*perm[n][k][s];  pre[n][o] = max_s acc[s]
// Register double-buffered software pipeline:
//   issue(n0,A) issue(n1,B) | comp(n0,A) issue(n2,A) | comp(n1,B)
//   issue(n3,B) | comp(n2,A) | comp(n3,B)
// Idx rows for all 4 points loaded in the prologue (2-step-ahead dependency
// for the ik readlanes).
// ---------------------------------------------------------------------------
__global__ __launch_bounds__(256, 4) void k_points(
    const float* __restrict__ pq,        // [M][128]
    const int*   __restrict__ nidx,      // [M][K]
    const float* __restrict__ perm,      // [M][K][KS]
    const float* __restrict__ conv_b,    // [OC]
    float* __restrict__ pre,             // [M][OC]
    float* __restrict__ partials)        // [NBLK2][128]
{
    const int tid  = threadIdx.x;
    const int lane = tid & 63;
    const int w    = tid >> 6;
    const int wg   = (int)blockIdx.x * 4 + w;   // wave id 0..8191

    const float bias = conv_b[lane];
    float sum = 0.f, sumsq = 0.f;

    int iv0 = 0, iv1 = 0, iv2 = 0, iv3 = 0;
    if (lane < 20) {
        iv0 = nidx[(size_t)wg * K_ + lane];
        iv1 = nidx[(size_t)(wg +     NWAVE2) * K_ + lane];
        iv2 = nidx[(size_t)(wg + 2 * NWAVE2) * K_ + lane];
        iv3 = nidx[(size_t)(wg + 3 * NWAVE2) * K_ + lane];
    }

    Pt A, B;
    issue_point(wg,                  lane, iv0, pq, perm, A);
    issue_point(wg +     NWAVE2,     lane, iv1, pq, perm, B);
    compute_point(wg,                lane, bias, A, pre, sum, sumsq);
    issue_point(wg + 2 * NWAVE2,     lane, iv2, pq, perm, A);
    compute_point(wg +     NWAVE2,   lane, bias, B, pre, sum, sumsq);
    issue_point(wg + 3 * NWAVE2,     lane, iv3, pq, perm, B);
    compute_point(wg + 2 * NWAVE2,   lane, bias, A, pre, sum, sumsq);
    compute_point(wg + 3 * NWAVE2,   lane, bias, B, pre, sum, sumsq);

    // block-level BN partial reduction: 4MB -> 1MB partials
    __shared__ float red[512];
    red[w * 128 + lane]      = sum;
    red[w * 128 + 64 + lane] = sumsq;
    __syncthreads();
    if (tid < 128) {
        float s = red[tid] + red[128 + tid] + red[256 + tid] + red[384 + tid];
        partials[(size_t)blockIdx.x * 128 + tid] = s;
    }
}

#undef KSTEP
#undef KSTEP0
#undef KS1
#undef KSI

// ---------------------------------------------------------------------------
// K2b: reduce partials per channel, fold BN+gamma/beta into scale/shift.
// ---------------------------------------------------------------------------
__global__ __launch_bounds__(256) void k_stats(
    const float* __restrict__ partials,  // [NBLK2][128]
    const float* __restrict__ gamma,
    const float* __restrict__ beta,
    float* __restrict__ stats)           // [128]
{
    const int ch  = blockIdx.x;          // 0..63
    const int tid = threadIdx.x;
    double s = 0.0, s2 = 0.0;
    for (int w = tid; w < NBLK2; w += 256) {
        s  += (double)partials[(size_t)w * 128 + ch];
        s2 += (double)partials[(size_t)w * 128 + 64 + ch];
    }
    __shared__ double sh_s[256];
    __shared__ double sh_q[256];
    sh_s[tid] = s; sh_q[tid] = s2;
    __syncthreads();
    for (int off = 128; off > 0; off >>= 1) {
        if (tid < off) { sh_s[tid] += sh_s[tid + off]; sh_q[tid] += sh_q[tid + off]; }
        __syncthreads();
    }
    if (tid == 0) {
        const double inv_n = 1.0 / (double)M_;
        double mean = sh_s[0] * inv_n;
        double var  = sh_q[0] * inv_n - mean * mean;
        double inv  = 1.0 / sqrt(var + 1e-5);
        double sc   = (double)gamma[ch] * inv;
        stats[ch]      = (float)sc;
        stats[64 + ch] = (float)((double)beta[ch] - mean * sc);
    }
}

// ---------------------------------------------------------------------------
// K3: y = pre*scale + shift, transposed [M][OC] -> [B][OC][N] via LDS 64x65.
// ---------------------------------------------------------------------------
__global__ __launch_bounds__(256) void k_apply(
    const float* __restrict__ pre,     // [M][OC]
    const float* __restrict__ stats,   // [128]
    float* __restrict__ out)           // [B][OC][N]
{
    __shared__ float tile[64 * 65];
    __shared__ float scl[64];
    __shared__ float shf[64];
    const int tid = threadIdx.x;
    if (tid < 64)       scl[tid]      = stats[tid];
    else if (tid < 128) shf[tid - 64] = stats[tid];
    __syncthreads();
    const int b  = blockIdx.x >> 5;
    const int pt = (blockIdx.x & 31) * 64;
    const int c  = tid & 63;
    const int r0 = tid >> 6;
    #pragma unroll
    for (int i = 0; i < 16; ++i) {
        const int r = i * 4 + r0;
        float v = pre[((size_t)(b * 2048 + pt + r)) * 64 + c];
        tile[c * 65 + r] = fmaf(v, scl[c], shf[c]);
    }
    __syncthreads();
    #pragma unroll
    for (int i = 0; i < 16; ++i) {
        const int o = i * 4 + r0;
        out[((size_t)(b * 64 + o)) * 2048 + pt + c] = tile[o * 65 + c];
    }
}

extern "C" void kernel_launch(void* const* d_in, const int* in_sizes, int n_in,
                              void* d_out, int out_size, void* d_ws, size_t ws_size,
                              hipStream_t stream) {
    const float* feat   = (const float*)d_in[0];
    const int*   nidx   = (const int*)  d_in[1];
    const float* perm   = (const float*)d_in[2];
    const float* conv_w = (const float*)d_in[3];
    const float* conv_b = (const float*)d_in[4];
    const float* gamma  = (const float*)d_in[5];
    const float* beta   = (const float*)d_in[6];
    float* out = (float*)d_out;

    char* ws = (char*)d_ws;
    float* pq       = (float*)ws;                                    // 16 MiB
    float* pre      = (float*)(ws + (size_t)M_ * 128 * 4);           //  8 MiB
    float* partials = (float*)(ws + (size_t)M_ * 128 * 4
                                  + (size_t)M_ * 64 * 4);            //  1 MiB
    float* stats    = (float*)(ws + (size_t)M_ * 128 * 4
                                  + (size_t)M_ * 64 * 4
                                  + (size_t)NBLK2 * 128 * 4);        // 512 B

    hipLaunchKernelGGL(k_project, dim3(512),  dim3(256), 0, stream, feat, conv_w, pq);
    hipLaunchKernelGGL(k_points,  dim3(2048), dim3(256), 0, stream, pq, nidx, perm,
                       conv_b, pre, partials);
    hipLaunchKernelGGL(k_stats,   dim3(64),   dim3(256), 0, stream, partials, gamma,
                       beta, stats);
    hipLaunchKernelGGL(k_apply,   dim3(512),  dim3(256), 0, stream, pre, stats, out);
}